// Round 3
// baseline (307.633 us; speedup 1.0000x reference)
//
#include <hip/hip_runtime.h>
#include <hip/hip_bf16.h>

// PointPillarScatter: out[b, c, y, x] = feat[p, c] for valid pillar p at
// (b, x, y, z); everything else zero. Output [B, C*nz, ny, nx] fp32.
//
// Fused gather formulation (no RMW scatter traffic):
//   1. cellmap[B*G] = -1                        (3.4 MB memset in d_ws)
//   2. cellmap[b*G + x + y*nx + z] = p          (48K threads)
//   3. dense fill: every out element written once, coalesced float4;
//      value = cellmap[cell] >= 0 ? feat[p*C + c] : 0
// Host cannot read device scalars (graph capture), so grid dims use only
// C (from in_sizes) and out_size; b is recovered from u0 = b*G + cell via a
// short ladder loop (B is small). nz != 1 falls back to zero-fill + scatter.

__global__ void pp_build_map(const int* __restrict__ coords,
                             const int* __restrict__ mask,
                             const int* __restrict__ p_B,
                             const int* __restrict__ p_nx,
                             const int* __restrict__ p_ny,
                             const int* __restrict__ p_nz,
                             int* __restrict__ cellmap, int P) {
    const int p = blockIdx.x * blockDim.x + threadIdx.x;
    if (p >= P) return;
    if (mask[p] <= 0) return;                      // invalid -> dropped
    const int nx = *p_nx, ny = *p_ny, nz = *p_nz, B = *p_B;
    const long long G = (long long)nx * ny * nz;
    const int b = coords[4 * p + 0];
    const int x = coords[4 * p + 1];
    const int y = coords[4 * p + 2];
    const int z = coords[4 * p + 3];
    const long long idx = (long long)x + (long long)y * nx + z;
    const long long flat = (long long)b * G + idx;
    if (flat < 0 || flat >= (long long)B * G) return;   // mode='drop'
    cellmap[flat] = p;
}

// gridDim.x * 256 covers BG/4 chunks (u0 = 4*chunk in [0, BG)); gridDim.y = C.
__global__ void pp_dense_fill(const float* __restrict__ feat,
                              const int* __restrict__ cellmap,
                              const int* __restrict__ p_nx,
                              const int* __restrict__ p_ny,
                              const int* __restrict__ p_nz,
                              float* __restrict__ out, int BG, int C) {
    const int u0 = 4 * (blockIdx.x * blockDim.x + threadIdx.x);
    const int c = blockIdx.y;
    if (u0 >= BG) return;
    const int nz = *p_nz;
    if (nz != 1) {
        // zero-fill only (linear, c-major covers out exactly once);
        // pp_scatter_general completes the pillar writes afterwards.
        *(float4*)(out + (size_t)c * BG + u0) = make_float4(0.f, 0.f, 0.f, 0.f);
        return;
    }
    const int G = (*p_nx) * (*p_ny);
    // b = u0 / G without integer division: B is small, ladder is exact.
    int b = 0, base = G;
    while (u0 >= base) { base += G; ++b; }
    const int cell0 = u0 - (base - G);             // u0 - b*G
    const int4 pm = *(const int4*)(cellmap + u0);  // 16B aligned: u0 % 4 == 0
    float4 v;
    v.x = (pm.x >= 0) ? feat[(size_t)pm.x * C + c] : 0.0f;
    v.y = (pm.y >= 0) ? feat[(size_t)pm.y * C + c] : 0.0f;
    v.z = (pm.z >= 0) ? feat[(size_t)pm.z * C + c] : 0.0f;
    v.w = (pm.w >= 0) ? feat[(size_t)pm.w * C + c] : 0.0f;
    // out[b, c, y, x] flat = (b*C + c)*G + cell ; G % 4 == 0 -> aligned
    *(float4*)(out + (size_t)(b * C + c) * G + cell0) = v;
}

// Round-1 scatter. only_general != 0 => act only when nz != 1 (fused path);
// only_general == 0 => always act (fallback path, after out memset).
__global__ void pp_scatter_general(const float* __restrict__ feat,
                                   const int* __restrict__ coords,
                                   const int* __restrict__ mask,
                                   const int* __restrict__ p_B,
                                   const int* __restrict__ p_nx,
                                   const int* __restrict__ p_ny,
                                   const int* __restrict__ p_nz,
                                   float* __restrict__ out,
                                   int P, int C, int only_general) {
    const int tid = blockIdx.x * blockDim.x + threadIdx.x;
    const int p = tid / C;
    const int c = tid - p * C;
    if (p >= P) return;
    const int nz = *p_nz;
    if (only_general && nz == 1) return;
    if (mask[p] <= 0) return;
    const int nx = *p_nx, ny = *p_ny, B = *p_B;
    const int b = coords[4 * p + 0];
    const int x = coords[4 * p + 1];
    const int y = coords[4 * p + 2];
    const int z = coords[4 * p + 3];
    const long long G = (long long)nx * ny * nz;
    const long long idx = (long long)x + (long long)y * nx + z;
    const long long flat = (long long)b * G + idx;
    if (flat < 0 || flat >= (long long)B * G) return;
    const float v = feat[(long long)p * C + c];
    if (nz == 1) {
        out[((b * C + c) * ny + y) * nx + x] = v;
    } else {
        const long long lin = flat * C + c;
        const long long Cnz = (long long)C * nz;
        const long long c2 = lin % Cnz;
        long long t = lin / Cnz;
        const long long x2 = t % nx;  t /= nx;
        const long long y2 = t % ny;
        const long long b2 = t / ny;
        out[((b2 * Cnz + c2) * ny + y2) * nx + x2] = v;
    }
}

extern "C" void kernel_launch(void* const* d_in, const int* in_sizes, int n_in,
                              void* d_out, int out_size, void* d_ws, size_t ws_size,
                              hipStream_t stream) {
    const float* feat   = (const float*)d_in[0];
    const int*   coords = (const int*)d_in[1];
    const int*   mask   = (const int*)d_in[2];
    const int*   p_B    = (const int*)d_in[3];
    const int*   p_nx   = (const int*)d_in[4];
    const int*   p_ny   = (const int*)d_in[5];
    const int*   p_nz   = (const int*)d_in[6];

    const int P = in_sizes[1] / 4;          // coords [P, 4]
    const int C = in_sizes[0] / P;          // features [P, C]
    const int BG = out_size / C;            // B*G
    float* out = (float*)d_out;

    const bool fused_ok = (ws_size >= (size_t)BG * sizeof(int)) &&
                          (BG % 4 == 0) && (out_size % 4 == 0) && (BG / C >= 0);

    const int block = 256;

    if (fused_ok) {
        int* cellmap = (int*)d_ws;
        hipMemsetAsync(cellmap, 0xFF, (size_t)BG * sizeof(int), stream);  // -1
        pp_build_map<<<(P + block - 1) / block, block, 0, stream>>>(
            coords, mask, p_B, p_nx, p_ny, p_nz, cellmap, P);
        dim3 grid((BG / 4 + block - 1) / block, C, 1);
        pp_dense_fill<<<grid, block, 0, stream>>>(
            feat, cellmap, p_nx, p_ny, p_nz, out, BG, C);
        // completes pillar writes only when nz != 1 (no-op for the bench shape)
        const long long total = (long long)P * C;
        pp_scatter_general<<<(int)((total + block - 1) / block), block, 0, stream>>>(
            feat, coords, mask, p_B, p_nx, p_ny, p_nz, out, P, C, /*only_general=*/1);
    } else {
        hipMemsetAsync(out, 0, (size_t)out_size * sizeof(float), stream);
        const long long total = (long long)P * C;
        pp_scatter_general<<<(int)((total + block - 1) / block), block, 0, stream>>>(
            feat, coords, mask, p_B, p_nx, p_ny, p_nz, out, P, C, /*only_general=*/0);
    }
}

// Round 4
// 267.674 us; speedup vs baseline: 1.1493x; 1.1493x over previous
//
#include <hip/hip_runtime.h>
#include <hip/hip_bf16.h>

// PointPillarScatter: out[b, c, y, x] = feat[p, c] for valid pillar p at
// (b, x, y, z); everything else zero. Output [B, C*nz, ny, nx] fp32.
//
// Minimal structure: hipMemsetAsync zero-fill (219 MB @ ~6.6 TB/s measured
// for the rocclr fill) + one scatter kernel, thread per (pillar, 4 channels).
// The scatter's 3.07M random 4B stores RMW lines that the memset just wrote
// -> served from L3 (output fits in 256 MB Infinity Cache), no extra HBM pass.

// Fast path: C % 4 == 0 (bench: C=64). 16 threads per pillar, each does one
// coalesced float4 feature read + 4 plane-strided stores.
__global__ void pp_scatter_v4(const float* __restrict__ feat,
                              const int* __restrict__ coords,
                              const int* __restrict__ mask,
                              const int* __restrict__ p_B,
                              const int* __restrict__ p_nx,
                              const int* __restrict__ p_ny,
                              const int* __restrict__ p_nz,
                              float* __restrict__ out,
                              int P, int C) {
    const int C4 = C >> 2;
    const int tid = blockIdx.x * blockDim.x + threadIdx.x;
    const int p = tid / C4;
    const int c = (tid - p * C4) << 2;
    if (p >= P) return;
    if (mask[p] <= 0) return;                       // invalid -> dropped

    const int nx = *p_nx, ny = *p_ny, nz = *p_nz, B = *p_B;
    const int b = coords[4 * p + 0];
    const int x = coords[4 * p + 1];
    const int y = coords[4 * p + 2];
    const int z = coords[4 * p + 3];

    const long long G = (long long)nx * ny * nz;
    const long long flat = (long long)b * G + (long long)x + (long long)y * nx + z;
    if (flat < 0 || flat >= (long long)B * G) return;   // mode='drop'

    const float4 v = *(const float4*)(feat + (size_t)p * C + c);  // coalesced

    if (nz == 1) {
        // out[b, c, y, x] flat = ((b*C + c)*ny + y)*nx + x, planes stride G
        const size_t Gp = (size_t)nx * ny;
        float* o = out + (size_t)(b * C + c) * Gp + (size_t)y * nx + x;
        o[0]      = v.x;
        o[Gp]     = v.y;
        o[2 * Gp] = v.z;
        o[3 * Gp] = v.w;
    } else {
        const float vv[4] = {v.x, v.y, v.z, v.w};
        const long long Cnz = (long long)C * nz;
        for (int j = 0; j < 4; ++j) {
            const long long lin = flat * C + (c + j);
            const long long c2 = lin % Cnz;
            long long t = lin / Cnz;
            const long long x2 = t % nx;  t /= nx;
            const long long y2 = t % ny;
            const long long b2 = t / ny;
            out[((b2 * Cnz + c2) * ny + y2) * nx + x2] = vv[j];
        }
    }
}

// Scalar fallback for C % 4 != 0: one thread per (p, c).
__global__ void pp_scatter_v1(const float* __restrict__ feat,
                              const int* __restrict__ coords,
                              const int* __restrict__ mask,
                              const int* __restrict__ p_B,
                              const int* __restrict__ p_nx,
                              const int* __restrict__ p_ny,
                              const int* __restrict__ p_nz,
                              float* __restrict__ out,
                              int P, int C) {
    const int tid = blockIdx.x * blockDim.x + threadIdx.x;
    const int p = tid / C;
    const int c = tid - p * C;
    if (p >= P) return;
    if (mask[p] <= 0) return;
    const int nx = *p_nx, ny = *p_ny, nz = *p_nz, B = *p_B;
    const int b = coords[4 * p + 0];
    const int x = coords[4 * p + 1];
    const int y = coords[4 * p + 2];
    const int z = coords[4 * p + 3];
    const long long G = (long long)nx * ny * nz;
    const long long flat = (long long)b * G + (long long)x + (long long)y * nx + z;
    if (flat < 0 || flat >= (long long)B * G) return;
    const float v = feat[(size_t)p * C + c];
    if (nz == 1) {
        out[((size_t)(b * C + c) * ny + y) * nx + x] = v;
    } else {
        const long long lin = flat * C + c;
        const long long Cnz = (long long)C * nz;
        const long long c2 = lin % Cnz;
        long long t = lin / Cnz;
        const long long x2 = t % nx;  t /= nx;
        const long long y2 = t % ny;
        const long long b2 = t / ny;
        out[((b2 * Cnz + c2) * ny + y2) * nx + x2] = v;
    }
}

extern "C" void kernel_launch(void* const* d_in, const int* in_sizes, int n_in,
                              void* d_out, int out_size, void* d_ws, size_t ws_size,
                              hipStream_t stream) {
    const float* feat   = (const float*)d_in[0];
    const int*   coords = (const int*)d_in[1];
    const int*   mask   = (const int*)d_in[2];
    const int*   p_B    = (const int*)d_in[3];
    const int*   p_nx   = (const int*)d_in[4];
    const int*   p_ny   = (const int*)d_in[5];
    const int*   p_nz   = (const int*)d_in[6];

    const int P = in_sizes[1] / 4;          // coords [P, 4]
    const int C = in_sizes[0] / P;          // features [P, C]
    float* out = (float*)d_out;

    // Dense zero fill — the roofline term (~219 MB @ ~6.6 TB/s measured).
    hipMemsetAsync(out, 0, (size_t)out_size * sizeof(float), stream);

    const int block = 256;
    if ((C & 3) == 0) {
        const long long total = (long long)P * (C >> 2);
        pp_scatter_v4<<<(int)((total + block - 1) / block), block, 0, stream>>>(
            feat, coords, mask, p_B, p_nx, p_ny, p_nz, out, P, C);
    } else {
        const long long total = (long long)P * C;
        pp_scatter_v1<<<(int)((total + block - 1) / block), block, 0, stream>>>(
            feat, coords, mask, p_B, p_nx, p_ny, p_nz, out, P, C);
    }
}

// Round 5
// 245.695 us; speedup vs baseline: 1.2521x; 1.0895x over previous
//
#include <hip/hip_runtime.h>
#include <hip/hip_bf16.h>

// PointPillarScatter, fused single-pass: out[b, c, y, x] = feat[p, c] for
// valid pillar p at (b, x, y); zeros elsewhere. Output [B, C, ny, nx] fp32.
//
// The output (219 MB) must be written once per call; rocclr fill streams NT
// so a memset+scatter pays an extra ~390 MB RMW line traffic for the 3M
// random 4B stores (measured ~60 us). Instead: cellmap[B*G] -> one dense
// pass that writes every output element exactly once, coalesced float4:
//   thread = (cell quad u0, channel slice); reads cellmap int4 once,
//   gathers occupied pillar rows (float4), 4x4 register transpose,
//   stores float4 per channel plane (consecutive threads -> consecutive
//   cells -> fully coalesced).

__global__ void pp_build_map(const int* __restrict__ coords,
                             const int* __restrict__ mask,
                             const int* __restrict__ p_B,
                             const int* __restrict__ p_nx,
                             const int* __restrict__ p_ny,
                             const int* __restrict__ p_nz,
                             int* __restrict__ cellmap, int P) {
    const int p = blockIdx.x * blockDim.x + threadIdx.x;
    if (p >= P) return;
    if (mask[p] <= 0) return;                      // invalid -> dropped
    const int nx = *p_nx, ny = *p_ny, nz = *p_nz, B = *p_B;
    const long long G = (long long)nx * ny * nz;
    const int b = coords[4 * p + 0];
    const int x = coords[4 * p + 1];
    const int y = coords[4 * p + 2];
    const int z = coords[4 * p + 3];
    const long long flat = (long long)b * G + (long long)x + (long long)y * nx + z;
    if (flat < 0 || flat >= (long long)B * G) return;   // mode='drop'
    cellmap[flat] = p;
}

// gridDim.x covers BG/4 quads; gridDim.y = CS channel slices of CL channels.
__global__ void pp_dense_all(const float* __restrict__ feat,
                             const int* __restrict__ cellmap,
                             const int* __restrict__ p_nx,
                             const int* __restrict__ p_ny,
                             const int* __restrict__ p_nz,
                             float* __restrict__ out,
                             int BG, int C, int CL) {
    const int q = blockIdx.x * blockDim.x + threadIdx.x;
    const int u0 = q << 2;                       // first cell of the quad
    if (u0 >= BG) return;
    const int c_begin = blockIdx.y * CL;

    const int nz = *p_nz;
    if (nz != 1) {
        // Zero-fill only (linear coverage of out, exactly once); the general
        // scatter kernel completes the pillar writes afterwards.
        const float4 z4 = make_float4(0.f, 0.f, 0.f, 0.f);
        for (int k = 0; k < CL; ++k)
            *(float4*)(out + (size_t)(c_begin + k) * BG + u0) = z4;
        return;
    }

    const int G = (*p_nx) * (*p_ny);
    // b = u0 / G via short ladder (B is small); quad stays in one batch
    // because G % 4 == 0.
    int b = 0, base = G;
    while (u0 >= base) { base += G; ++b; }
    const int cell0 = u0 - (base - G);

    const int4 pm = *(const int4*)(cellmap + u0);          // 16B, u0 % 4 == 0
    const float* r0 = feat + (size_t)pm.x * C;
    const float* r1 = feat + (size_t)pm.y * C;
    const float* r2 = feat + (size_t)pm.z * C;
    const float* r3 = feat + (size_t)pm.w * C;

    float* obase = out + ((size_t)b * C + c_begin) * (size_t)G + cell0;
    const float4 z4 = make_float4(0.f, 0.f, 0.f, 0.f);

    #pragma unroll 4
    for (int c = 0; c < CL; c += 4) {
        float4 a = z4, d = z4, e = z4, f = z4;             // rows, ch c..c+3
        if (pm.x >= 0) a = *(const float4*)(r0 + c_begin + c);
        if (pm.y >= 0) d = *(const float4*)(r1 + c_begin + c);
        if (pm.z >= 0) e = *(const float4*)(r2 + c_begin + c);
        if (pm.w >= 0) f = *(const float4*)(r3 + c_begin + c);
        // 4x4 register transpose: channel c+j gets lane-quad (a,d,e,f)[j]
        *(float4*)(obase + (size_t)(c + 0) * G) = make_float4(a.x, d.x, e.x, f.x);
        *(float4*)(obase + (size_t)(c + 1) * G) = make_float4(a.y, d.y, e.y, f.y);
        *(float4*)(obase + (size_t)(c + 2) * G) = make_float4(a.z, d.z, e.z, f.z);
        *(float4*)(obase + (size_t)(c + 3) * G) = make_float4(a.w, d.w, e.w, f.w);
    }
}

// General-layout completion (nz != 1 only on the fused path; always on the
// fallback path). One thread per pillar, loops channels.
__global__ void pp_scatter_general(const float* __restrict__ feat,
                                   const int* __restrict__ coords,
                                   const int* __restrict__ mask,
                                   const int* __restrict__ p_B,
                                   const int* __restrict__ p_nx,
                                   const int* __restrict__ p_ny,
                                   const int* __restrict__ p_nz,
                                   float* __restrict__ out,
                                   int P, int C, int only_general) {
    const int p = blockIdx.x * blockDim.x + threadIdx.x;
    if (p >= P) return;
    const int nz = *p_nz;
    if (only_general && nz == 1) return;
    if (mask[p] <= 0) return;
    const int nx = *p_nx, ny = *p_ny, B = *p_B;
    const int b = coords[4 * p + 0];
    const int x = coords[4 * p + 1];
    const int y = coords[4 * p + 2];
    const int z = coords[4 * p + 3];
    const long long G = (long long)nx * ny * nz;
    const long long flat = (long long)b * G + (long long)x + (long long)y * nx + z;
    if (flat < 0 || flat >= (long long)B * G) return;
    for (int c = 0; c < C; ++c) {
        const float v = feat[(size_t)p * C + c];
        if (nz == 1) {
            out[((size_t)(b * C + c) * ny + y) * nx + x] = v;
        } else {
            const long long lin = flat * C + c;
            const long long Cnz = (long long)C * nz;
            const long long c2 = lin % Cnz;
            long long t = lin / Cnz;
            const long long x2 = t % nx;  t /= nx;
            const long long y2 = t % ny;
            const long long b2 = t / ny;
            out[((b2 * Cnz + c2) * ny + y2) * nx + x2] = v;
        }
    }
}

extern "C" void kernel_launch(void* const* d_in, const int* in_sizes, int n_in,
                              void* d_out, int out_size, void* d_ws, size_t ws_size,
                              hipStream_t stream) {
    const float* feat   = (const float*)d_in[0];
    const int*   coords = (const int*)d_in[1];
    const int*   mask   = (const int*)d_in[2];
    const int*   p_B    = (const int*)d_in[3];
    const int*   p_nx   = (const int*)d_in[4];
    const int*   p_ny   = (const int*)d_in[5];
    const int*   p_nz   = (const int*)d_in[6];

    const int P = in_sizes[1] / 4;          // coords [P, 4]
    const int C = in_sizes[0] / P;          // features [P, C]
    const int BG = out_size / C;            // B*G
    float* out = (float*)d_out;

    const int block = 256;
    const bool fused_ok = (ws_size >= (size_t)BG * sizeof(int)) &&
                          (BG % 4 == 0) && (C % 4 == 0);

    if (fused_ok) {
        int* cellmap = (int*)d_ws;
        hipMemsetAsync(cellmap, 0xFF, (size_t)BG * sizeof(int), stream);  // -1
        pp_build_map<<<(P + block - 1) / block, block, 0, stream>>>(
            coords, mask, p_B, p_nx, p_ny, p_nz, cellmap, P);

        const int CS = (C % 8 == 0) ? 2 : 1;     // channel slices
        const int CL = C / CS;
        dim3 grid((BG / 4 + block - 1) / block, CS, 1);
        pp_dense_all<<<grid, block, 0, stream>>>(
            feat, cellmap, p_nx, p_ny, p_nz, out, BG, C, CL);

        // no-op unless nz != 1 (188 tiny blocks)
        pp_scatter_general<<<(P + block - 1) / block, block, 0, stream>>>(
            feat, coords, mask, p_B, p_nx, p_ny, p_nz, out, P, C, 1);
    } else {
        hipMemsetAsync(out, 0, (size_t)out_size * sizeof(float), stream);
        pp_scatter_general<<<(P + block - 1) / block, block, 0, stream>>>(
            feat, coords, mask, p_B, p_nx, p_ny, p_nz, out, P, C, 0);
    }
}